// Round 11
// baseline (26.954 us; speedup 1.0000x reference)
//
#include <hip/hip_runtime.h>

#define FD 768
#define HD 256
#define NF 512
#define NC 512
#define PAIRS (NF * (NF - 1) / 2)   // 130816

typedef __attribute__((ext_vector_type(4))) float f32x4;
typedef __attribute__((ext_vector_type(8))) short bf16x8;

// RNE float->bf16, packed pair (a = low 16, b = high 16)
__device__ inline unsigned bf16pk(float a, float b) {
    unsigned ua = __float_as_uint(a), ub = __float_as_uint(b);
    ua = (ua + 0x7FFFu + ((ua >> 16) & 1u)) >> 16;
    ub = (ub + 0x7FFFu + ((ub >> 16) & 1u)) >> 16;
    return ua | (ub << 16);
}

// ---------------------------------------------------------------------------
// Kernel 1 (EXACT R10 code — validated, absmax 0.0156): C = E @ [W1top|W1bot]
// + [b1|0], bf16 MFMA, f32 accum. Grid 16x16, 32x32 tile, 4 waves, K=768 in
// 3 rounds of 256. Coalesced f4 staging for both E and W; XOR-swizzled LDS.
// D layout: lane l, reg p -> C[r0+16wr+(l&15)][c0+16wc+4(l>>4)+p]
// ---------------------------------------------------------------------------
__global__ __launch_bounds__(256) void gemm_mfma_kernel(
    const float* __restrict__ E, const float* __restrict__ W1,
    const float* __restrict__ b1, float* __restrict__ C)
{
    __shared__ char lds[2 * 32 * 512];          // Et 16KB + Wt 16KB
    char* EtB = lds;
    char* WtB = lds + 32 * 512;

    const int tid  = threadIdx.x;
    const int r0   = blockIdx.y * 32, c0 = blockIdx.x * 32;
    const int c0w4 = (c0 & 255) >> 2;           // f4 col offset within W half
    const int dofs = (c0 >= 256) ? FD : 0;
    const int lane = tid & 63, wave = tid >> 6;
    const int wr = wave >> 1, wc = wave & 1;
    const int m = lane & 15, g = lane >> 4;
    const int arow = 16 * wc + m;               // Wt row (= local C col)
    const int brow = 16 * wr + m;               // Et row (= local C row)

    f32x4 acc = {0.f, 0.f, 0.f, 0.f};
    const float4* E4  = (const float4*)E;       // row pitch 192 f4
    const float4* W14 = (const float4*)W1;      // row pitch 64 f4

    for (int rnd = 0; rnd < 3; ++rnd) {
        if (rnd) __syncthreads();               // LDS reuse guard

        // ---- stage Et: 32 rows x 256 k, f4 loads + packed b64 writes ----
        #pragma unroll
        for (int s = 0; s < 8; ++s) {
            int idx = tid + s * 256;            // 2048 f4
            int r = idx >> 6, c4 = idx & 63;    // k = 4*c4
            float4 v = E4[(size_t)(r0 + r) * 192 + rnd * 64 + c4];
            uint2 pk;
            pk.x = bf16pk(v.x, v.y);
            pk.y = bf16pk(v.z, v.w);
            int gi = (c4 >> 1) ^ (r & 7);
            *(uint2*)(EtB + r * 512 + gi * 16 + (c4 & 1) * 8) = pk;
        }
        // ---- stage Wt: coalesced f4 loads + b32 scatter ----
        #pragma unroll
        for (int it2 = 0; it2 < 4; ++it2) {
            int task = it2 * 256 + tid;         // 1024 = 8 c-quads x 128 kp
            int c4 = task & 7, kp = task >> 3;
            int d = dofs + rnd * 256 + 2 * kp;
            float4 w0 = W14[(size_t)d * 64 + c0w4 + c4];
            float4 w1 = W14[(size_t)(d + 1) * 64 + c0w4 + c4];
            float a0v[4] = {w0.x, w0.y, w0.z, w0.w};
            float a1v[4] = {w1.x, w1.y, w1.z, w1.w};
            #pragma unroll
            for (int u = 0; u < 4; ++u) {
                int c = 4 * c4 + u;
                unsigned pk = bf16pk(a0v[u], a1v[u]);
                int gi = (kp >> 2) ^ (c & 7);
                *(unsigned*)(WtB + c * 512 + gi * 16 + (kp & 3) * 4) = pk;
            }
        }
        __syncthreads();

        // ---- 8 mfma per wave (K chunk = 256) ----
        #pragma unroll
        for (int ks = 0; ks < 8; ++ks) {
            int giA = (4 * ks + g) ^ (arow & 7);
            int giB = (4 * ks + g) ^ (brow & 7);
            bf16x8 af = *(const bf16x8*)(WtB + arow * 512 + giA * 16);
            bf16x8 bf = *(const bf16x8*)(EtB + brow * 512 + giB * 16);
            acc = __builtin_amdgcn_mfma_f32_16x16x32_bf16(af, bf, acc, 0, 0, 0);
        }
    }

    const int row = r0 + 16 * wr + m;           // n = l&15
    const int col = c0 + 16 * wc + 4 * g;       // m = 4*(l>>4)+p
    float4 b = {0.f, 0.f, 0.f, 0.f};
    if (c0 < 256) b = ((const float4*)b1)[col >> 2];
    float4 o = {acc[0] + b.x, acc[1] + b.y, acc[2] + b.z, acc[3] + b.w};
    *(float4*)&C[(size_t)row * NC + col] = o;
}

// ---------------------------------------------------------------------------
// Kernel 2: pair scores. 16x32 tile, 272 blocks, 128 threads (2 waves),
// 2x2 microtile: 4 ds_read_b128 per k4 for 4 pairs (1.0 instr/pair vs 1.5).
// Per-pair k-accumulation order identical to R10's 1x2 -> bitwise-same
// scores. XOR swizzle key (row>>1)&7: a-reads 4 addrs / 4 quads (bcast),
// b-reads 16 addrs 2/quad = free. W2 via uniform s_load.
// ---------------------------------------------------------------------------
__global__ __launch_bounds__(128) void pair_kernel(
    const float* __restrict__ C, const float* __restrict__ W2,
    const float* __restrict__ b2, float* __restrict__ out)
{
    __shared__ float4 As[16 * 64];
    __shared__ float4 Bs[32 * 64];

    int rem = blockIdx.x, bi = 0;
    while (rem >= 16 - (bi >> 1)) { rem -= 16 - (bi >> 1); ++bi; }
    const int bj = (bi >> 1) + rem;
    const int i0 = bi * 16, j0 = bj * 32;

    const int tid = threadIdx.x;
    const float4* C4 = (const float4*)C;        // row pitch 128 f4

    #pragma unroll
    for (int s = 0; s < 8; ++s) {               // A: 16 rows x 64 f4
        int idx = tid + 128 * s;
        int row = idx >> 6, c4 = idx & 63;
        As[row * 64 + (c4 ^ ((row >> 1) & 7))] = C4[(i0 + row) * 128 + c4];
    }
    #pragma unroll
    for (int s = 0; s < 16; ++s) {              // B: 32 rows x 64 f4
        int idx = tid + 128 * s;
        int row = idx >> 6, c4 = idx & 63;
        Bs[row * 64 + (c4 ^ ((row >> 1) & 7))] = C4[(j0 + row) * 128 + 64 + c4];
    }
    __syncthreads();

    const int tx = tid & 15, ty = tid >> 4;     // j-pair 2tx.., i-pair 2ty..
    const int ka = ty & 7, kb = tx & 7;
    const float4* W24 = (const float4*)W2;

    float acc00 = 0.f, acc01 = 0.f, acc10 = 0.f, acc11 = 0.f;
    #pragma unroll 8
    for (int k4 = 0; k4 < HD / 4; ++k4) {
        float4 a0  = As[(2 * ty + 0) * 64 + (k4 ^ ka)];
        float4 a1  = As[(2 * ty + 1) * 64 + (k4 ^ ka)];
        float4 b0  = Bs[(2 * tx + 0) * 64 + (k4 ^ kb)];
        float4 b1v = Bs[(2 * tx + 1) * 64 + (k4 ^ kb)];
        float4 w = W24[k4];                     // uniform -> s_load
        #define PACC(ACC, A, B) \
            ACC = fmaf(fmaxf(A.x + B.x, 0.f), w.x, ACC); \
            ACC = fmaf(fmaxf(A.y + B.y, 0.f), w.y, ACC); \
            ACC = fmaf(fmaxf(A.z + B.z, 0.f), w.z, ACC); \
            ACC = fmaf(fmaxf(A.w + B.w, 0.f), w.w, ACC);
        PACC(acc00, a0, b0) PACC(acc01, a0, b1v)
        PACC(acc10, a1, b0) PACC(acc11, a1, b1v)
        #undef PACC
    }

    const float bias2 = b2[0];
    #pragma unroll
    for (int u = 0; u < 4; ++u) {
        int i = i0 + 2 * ty + (u >> 1);
        int j = j0 + 2 * tx + (u & 1);
        float v = (u == 0) ? acc00 : (u == 1) ? acc01 : (u == 2) ? acc10 : acc11;
        if (j > i) {
            int p = i * (2 * NF - i - 1) / 2 + (j - i - 1);
            out[p]             = (float)i;
            out[PAIRS + p]     = (float)j;
            out[2 * PAIRS + p] = v + bias2;
        }
    }
}

extern "C" void kernel_launch(void* const* d_in, const int* in_sizes, int n_in,
                              void* d_out, int out_size, void* d_ws, size_t ws_size,
                              hipStream_t stream) {
    const float* E  = (const float*)d_in[0];
    const float* W1 = (const float*)d_in[1];
    const float* b1 = (const float*)d_in[2];
    const float* W2 = (const float*)d_in[3];
    const float* b2 = (const float*)d_in[4];
    float* out = (float*)d_out;
    float* C   = (float*)d_ws;                  // 1 MiB

    gemm_mfma_kernel<<<dim3(16, 16), 256, 0, stream>>>(E, W1, b1, C);
    pair_kernel<<<272, 128, 0, stream>>>(C, W2, b2, out);
}